// Round 5
// baseline (65.748 us; speedup 1.0000x reference)
//
#include <hip/hip_runtime.h>
#include <stdint.h>

#define E2V     600000
#define NNODES  50000
#define UCNT    500
#define DE      100
#define DOUT    100
#define NB      16
#define KTOT    3328      // 3200 (G) + 100 (x/root) + 1 (bias) + 27 pad
#define KCH     104       // KTOT/32
#define CAP2    128       // per-slot edge list capacity (expected ~12, max ~35)
#define MROWS   512
#define HASHN   2048      // hash table (load factor 24%)

using short8 = __attribute__((ext_vector_type(8))) short;
using f32x4  = __attribute__((ext_vector_type(4))) float;

static constexpr size_t align256(size_t x){ return (x + 255) & ~size_t(255); }
static constexpr size_t OFF_HKEY = 0;                                        // 2048 i32
static constexpr size_t OFF_HVAL = align256(OFF_HKEY + HASHN*4);             // 2048 i32
static constexpr size_t OFF_IHEA = align256(OFF_HVAL + HASHN*4);             // 512 i32
static constexpr size_t OFF_INEX = OFF_IHEA + MROWS*4;                       // 512 i32
static constexpr size_t OFF_SCNT = OFF_INEX + MROWS*4;                       // 512 i32
static constexpr size_t OFF_EL2  = align256(OFF_SCNT + MROWS*4);             // 512*128 i32
static constexpr size_t OFF_GM   = align256(OFF_EL2 + (size_t)MROWS*CAP2*4); // 512*3328 bf16
static constexpr size_t OFF_GS   = OFF_GM + (size_t)MROWS*KTOT*2;
static constexpr size_t OFF_BTM  = align256(OFF_GS + (size_t)MROWS*KTOT*2);  // 100*3328 bf16
static constexpr size_t OFF_BTS  = OFF_BTM + (size_t)DOUT*KTOT*2;            // total ~8.3 MB

#define TR_BLOCKS  (KCH * 4 * 2)     // 832 transpose tiles

__device__ __forceinline__ unsigned short f2b(float f){
    uint32_t u = __float_as_uint(f);
    uint32_t r = (u + 0x7FFFu + ((u >> 16) & 1u)) >> 16;
    return (unsigned short)r;
}

__device__ __forceinline__ uint32_t hslot(int key){
    return (((uint32_t)key * 2654435761u) >> 16) & (HASHN - 1);
}
__device__ __forceinline__ int hash_lookup(const int* __restrict__ hkey,
                                           const int* __restrict__ hval, int key){
    uint32_t idx = hslot(key);
    while (true){
        int k = hkey[idx];
        if (k == key) return hval[idx];
        if (k == -1)  return -1;
        idx = (idx + 1) & (HASHN - 1);
    }
}

__device__ __forceinline__ float bt_src(const float* __restrict__ basis,
                                        const float* __restrict__ root,
                                        const float* __restrict__ bias,
                                        int k, int j){
    if (j >= 100) return 0.f;
    if (k < 3200) return basis[k*100 + j];
    if (k < 3300) return root[(k-3200)*100 + j];
    if (k == 3300) return bias[j];
    return 0.f;
}

// ---- K1: Bt transpose (blocks 0..831) ∥ hash build + inverse chains + scnt (block 832) ----
__global__ __launch_bounds__(256) void k_setup(
        const int* __restrict__ unseen_index,
        int* __restrict__ hkey, int* __restrict__ hval,
        int* __restrict__ ihead, int* __restrict__ inext, int* __restrict__ scnt,
        const float* __restrict__ bm, const float* __restrict__ bs,
        const float* __restrict__ rm, const float* __restrict__ rs,
        const float* __restrict__ qm, const float* __restrict__ qs,
        unsigned short* __restrict__ btm, unsigned short* __restrict__ bts){
    int bx = blockIdx.x;
    int tid = threadIdx.x;
    if (bx == TR_BLOCKS){
        // init tables
        for (int i = tid; i < HASHN; i += 256){ hkey[i] = -1; hval[i] = -1; }
        for (int i = tid; i < MROWS; i += 256){ ihead[i] = -1; scnt[i] = 0; }
        __syncthreads();
        // insert 500 (last-wins via atomicMax on val)
        for (int u = tid; u < UCNT; u += 256){
            int key = unseen_index[u];
            uint32_t idx = hslot(key);
            while (true){
                int k = hkey[idx];
                if (k == key){ atomicMax(&hval[idx], u); break; }
                if (k == -1){
                    int old = atomicCAS(&hkey[idx], -1, key);
                    if (old == -1 || old == key){ atomicMax(&hval[idx], u); break; }
                }
                idx = (idx + 1) & (HASHN - 1);
            }
        }
        __syncthreads();
        // inverse chains: slot -> list of u
        for (int u = tid; u < UCNT; u += 256){
            int slot = hash_lookup(hkey, hval, unseen_index[u]);
            inext[u] = atomicExch(&ihead[slot], u);
        }
        return;
    }
    // transpose tiles: B_aug^T [j][k] bf16
    int kt = bx % KCH, jt = (bx / KCH) & 3, br = bx / (KCH*4);
    const float* basis = br ? bs : bm;
    const float* root  = br ? rs : rm;
    const float* bias  = br ? qs : qm;
    unsigned short* bt = br ? bts : btm;
    int k0 = kt*32, j0 = jt*32;
    __shared__ float tile[32][33];
    int tx = tid & 31, ty = tid >> 5;
    for (int r = ty; r < 32; r += 8)
        tile[r][tx] = bt_src(basis, root, bias, k0 + r, j0 + tx);
    __syncthreads();
    for (int r = ty; r < 32; r += 8){
        int j = j0 + r;
        if (j < 100) bt[(size_t)j*KTOT + k0 + tx] = f2b(tile[tx][r]);
    }
}

// ---- K2: filter edges with unseen dst -> per-slot lists ----
__global__ void k_filter(const int* __restrict__ eidx,
                         const int* __restrict__ hkey, const int* __restrict__ hval,
                         int* __restrict__ scnt, int* __restrict__ elist){
    int e = threadIdx.x + blockIdx.x * 256;
    if (e >= E2V) return;
    int slot = hash_lookup(hkey, hval, eidx[E2V + e]);
    if (slot >= 0){
        int pos = atomicAdd(&scnt[slot], 1);
        if (pos < CAP2) elist[slot * CAP2 + pos] = e;
    }
}

// ---- K3: build G rows: G[slot] = [ (1/cnt)*sum_e att[t_e]⊗m_e | x | 1 | 0 ] bf16 ----
__global__ __launch_bounds__(256) void k_g(
        const int* __restrict__ scnt, const int* __restrict__ elist,
        const int* __restrict__ hkey, const int* __restrict__ hval,
        const int* __restrict__ eidx,
        const int* __restrict__ etype, const int* __restrict__ rel_index,
        const int* __restrict__ node_id,
        const float* __restrict__ ent, const float* __restrict__ unseen,
        const float* __restrict__ rel,
        const float* __restrict__ am, const float* __restrict__ as_,
        unsigned short* __restrict__ Gm, unsigned short* __restrict__ Gs){
    int slot = blockIdx.x;
    int tid  = threadIdx.x;
    int nE = (slot < UCNT) ? scnt[slot] : 0;
    if (nE > CAP2) nE = CAP2;
    __shared__ __align__(16) float sM[8][200];
    __shared__ __align__(16) float sAm[8][16], sAs[8][16];
    __shared__ const float* sPX[8];
    __shared__ const float* sPR[8];
    __shared__ int sT[8];
    float gm[16], gs[16];
    #pragma unroll
    for (int b = 0; b < NB; ++b){ gm[b] = 0.f; gs[b] = 0.f; }

    for (int c0 = 0; c0 < nE; c0 += 8){
        int kc = nE - c0; if (kc > 8) kc = 8;
        if (tid < kc){
            int e = elist[slot*CAP2 + c0 + tid];
            sT[tid] = etype[e];
            int s = eidx[e];
            int p = hash_lookup(hkey, hval, s);
            sPX[tid] = (p >= 0) ? unseen + (size_t)p*DE : ent + (size_t)node_id[s]*DE;
            sPR[tid] = rel + (size_t)rel_index[e]*DE;
        }
        __syncthreads();
        for (int q = tid; q < kc*50; q += 256){
            int eL = q / 50, s = q % 50;
            const float* base = (s < 25) ? sPX[eL] : sPR[eL];
            int off = (s < 25) ? s*4 : (s-25)*4;
            float4 v = *(const float4*)(base + off);
            int kb = (s < 25) ? s*4 : (s-25)*4 + 100;
            *(float4*)&sM[eL][kb] = v;
        }
        if (tid < kc*16){
            int eL = tid >> 4, b = tid & 15;
            int t = sT[eL];
            sAm[eL][b] = am[t*NB + b];
            sAs[eL][b] = as_[t*NB + b];
        }
        __syncthreads();
        if (tid < 200){
            for (int e = 0; e < kc; ++e){
                float mk = sM[e][tid];
                const float4* pa = (const float4*)&sAm[e][0];
                const float4* ps = (const float4*)&sAs[e][0];
                #pragma unroll
                for (int q = 0; q < 4; ++q){
                    float4 va = pa[q], vs = ps[q];
                    gm[q*4+0] += va.x*mk; gm[q*4+1] += va.y*mk;
                    gm[q*4+2] += va.z*mk; gm[q*4+3] += va.w*mk;
                    gs[q*4+0] += vs.x*mk; gs[q*4+1] += vs.y*mk;
                    gs[q*4+2] += vs.z*mk; gs[q*4+3] += vs.w*mk;
                }
            }
        }
        __syncthreads();
    }
    size_t row = (size_t)slot * KTOT;
    float inv = 1.f / fmaxf((float)nE, 1.f);
    if (tid < 200){
        #pragma unroll
        for (int b = 0; b < NB; ++b){
            Gm[row + b*200 + tid] = f2b(gm[b] * inv);
            Gs[row + b*200 + tid] = f2b(gs[b] * inv);
        }
    }
    if (tid < 100){
        float xv = (slot < UCNT) ? unseen[(size_t)slot*DE + tid] : 0.f;
        unsigned short h = f2b(xv);
        Gm[row + 3200 + tid] = h; Gs[row + 3200 + tid] = h;
    } else if (tid == 100){
        Gm[row + 3300] = f2b(1.f); Gs[row + 3300] = f2b(1.f);
    } else if (tid > 100 && tid < 128){
        Gm[row + 3200 + tid] = 0; Gs[row + 3200 + tid] = 0;   // 3301..3327
    }
}

// ---- K4: out = G_aug @ B_aug (bf16 MFMA), direct scatter to the 3 output blocks ----
__global__ __launch_bounds__(256) void k_gemm(
        const unsigned short* __restrict__ Gm, const unsigned short* __restrict__ Gs,
        const unsigned short* __restrict__ Btm, const unsigned short* __restrict__ Bts,
        const int* __restrict__ ihead, const int* __restrict__ inext,
        float* __restrict__ out){
    int wid = blockIdx.x * 4 + (threadIdx.x >> 6);     // 0..447
    int lane = threadIdx.x & 63;
    int br = wid / 224;
    int w2 = wid % 224;
    int m16 = w2 & 31;                                  // 32 M-tiles of 16 rows
    int jt  = w2 >> 5;                                  // 7 j-tiles
    const unsigned short* A  = br ? Gs : Gm;
    const unsigned short* Bt = br ? Bts : Btm;
    int rowa = lane & 15, ko = (lane >> 4) * 8;
    int j0 = (jt == 6) ? 84 : jt*16;                    // overlap trick, guard col>=96
    int col = j0 + rowa;
    const unsigned short* ap = A  + (size_t)(m16*16 + rowa)*KTOT + ko;
    const unsigned short* bp = Bt + (size_t)col*KTOT + ko;
    f32x4 acc = {0.f, 0.f, 0.f, 0.f};
    #pragma unroll 8
    for (int kc = 0; kc < KCH; ++kc){
        short8 av = *(const short8*)(ap + kc*32);
        short8 bv = *(const short8*)(bp + kc*32);
        acc = __builtin_amdgcn_mfma_f32_16x16x32_bf16(av, bv, acc, 0, 0, 0);
    }
    if (jt < 6 || col >= 96){
        int r0 = m16*16 + (lane >> 4)*4;
        #pragma unroll
        for (int r = 0; r < 4; ++r){
            int row = r0 + r;
            int u = ihead[row];
            while (u >= 0){
                if (br == 0){
                    out[(size_t)u*100 + col] = acc[r];
                    out[(size_t)(UCNT + u)*100 + col] = acc[r];
                } else {
                    out[(size_t)(2*UCNT + u)*100 + col] = acc[r];
                }
                u = inext[u];
            }
        }
    }
}

extern "C" void kernel_launch(void* const* d_in, const int* in_sizes, int n_in,
                              void* d_out, int out_size, void* d_ws, size_t ws_size,
                              hipStream_t stream){
    const float* ent        = (const float*)d_in[0];
    const float* rel_table  = (const float*)d_in[1];
    const float* unseen_emb = (const float*)d_in[2];
    const float* att_mu     = (const float*)d_in[3];
    const float* basis_mu   = (const float*)d_in[4];
    const float* root_mu    = (const float*)d_in[5];
    const float* bias_mu    = (const float*)d_in[6];
    const float* att_sig    = (const float*)d_in[7];
    const float* basis_sig  = (const float*)d_in[8];
    const float* root_sig   = (const float*)d_in[9];
    const float* bias_sig   = (const float*)d_in[10];
    const int* node_id      = (const int*)d_in[11];
    const int* edge_index   = (const int*)d_in[12];
    const int* edge_type    = (const int*)d_in[13];
    const int* rel_index    = (const int*)d_in[14];
    const int* unseen_index = (const int*)d_in[15];
    float* out = (float*)d_out;
    char* ws = (char*)d_ws;

    int* hkey  = (int*)(ws + OFF_HKEY);
    int* hval  = (int*)(ws + OFF_HVAL);
    int* ihead = (int*)(ws + OFF_IHEA);
    int* inext = (int*)(ws + OFF_INEX);
    int* scnt  = (int*)(ws + OFF_SCNT);
    int* elist = (int*)(ws + OFF_EL2);
    unsigned short* Gm  = (unsigned short*)(ws + OFF_GM);
    unsigned short* Gs  = (unsigned short*)(ws + OFF_GS);
    unsigned short* Btm = (unsigned short*)(ws + OFF_BTM);
    unsigned short* Bts = (unsigned short*)(ws + OFF_BTS);

    k_setup<<<TR_BLOCKS + 1, 256, 0, stream>>>(unseen_index, hkey, hval,
        ihead, inext, scnt, basis_mu, basis_sig, root_mu, root_sig,
        bias_mu, bias_sig, Btm, Bts);
    k_filter<<<(E2V + 255)/256, 256, 0, stream>>>(edge_index, hkey, hval, scnt, elist);
    k_g<<<MROWS, 256, 0, stream>>>(scnt, elist, hkey, hval, edge_index, edge_type,
        rel_index, node_id, ent, unseen_emb, rel_table, att_mu, att_sig, Gm, Gs);
    k_gemm<<<112, 256, 0, stream>>>(Gm, Gs, Btm, Bts, ihead, inext, out);
}